// Round 12
// baseline (253.823 us; speedup 1.0000x reference)
//
#include <hip/hip_runtime.h>
#include <cmath>

#define HID 64
typedef unsigned short ushort_t;
typedef __attribute__((ext_vector_type(8))) short bf16x8;
typedef __attribute__((ext_vector_type(4))) float f32x4;

__device__ inline ushort_t f2b(float f) {
    unsigned u = __float_as_uint(f);
    unsigned r = (u + 0x7fffu + ((u >> 16) & 1u)) >> 16;
    return (ushort_t)r;
}
__device__ inline float b2f(ushort_t b) { return __uint_as_float(((unsigned)b) << 16); }

// ---------------- fills ----------------

__global__ void fill_i32(int* __restrict__ p, int v, long n) {
    long i = (long)blockIdx.x * blockDim.x + threadIdx.x;
    long stride = (long)gridDim.x * blockDim.x;
    for (; i < n; i += stride) p[i] = v;
}

// ---------------- prep: transposes + zero d_out + batch hist + edge count ----------
__global__ __launch_bounds__(256) void prep_k(const float* __restrict__ W1,
                                              const float* __restrict__ W2,
                                              ushort_t* __restrict__ W1t,
                                              ushort_t* __restrict__ W2t,
                                              const int* __restrict__ batch,
                                              int* __restrict__ cnt_i,
                                              float* __restrict__ outp,
                                              const int* __restrict__ ei,
                                              int* __restrict__ deg,
                                              int N, int E, int NHB) {
    int b = blockIdx.x;
    int t = threadIdx.x;
    if (b < 128) {
        W1t[(size_t)t * 128 + b] = f2b(W1[(size_t)b * 256 + t]);
    } else if (b < 384) {
        int k = b - 128;
        if (t < 64) W2t[(size_t)t * 256 + k] = f2b(W2[(size_t)k * 64 + t]);
    } else if (b == 384) {
        int i = t * 8;
        #pragma unroll
        for (int j = 0; j < 8; ++j) outp[i + j] = 0.f;
    } else if (b < 385 + NHB) {
        __shared__ int lh[32];
        if (t < 32) lh[t] = 0;
        __syncthreads();
        int i = (b - 385) * 256 + t;
        if (i < N) atomicAdd(&lh[batch[i]], 1);
        __syncthreads();
        if (t < 32 && lh[t] > 0) atomicAdd(&cnt_i[t], lh[t]);
    } else {
        int e = (b - 385 - NHB) * 256 + t;
        int T = E + N;
        if (e < T) {
            int d = (e < E) ? ei[E + e] : (e - E);
            atomicAdd(&deg[d], 1);
        }
    }
}

// ---------------- fused single-dispatch exclusive scan ----------------
// block b: base = sum(deg[0 .. b*256)), then local exclusive scan of its 256 elems.
__global__ __launch_bounds__(256) void scan_k(const int* __restrict__ deg,
                                              int* __restrict__ rowstart, int N) {
    int t = threadIdx.x;
    int lane = t & 63, wave = t >> 6;
    int limit = blockIdx.x * 256;
    int pv = 0;
    for (int i = t; i < limit; i += 256) pv += deg[i];
    #pragma unroll
    for (int off = 32; off > 0; off >>= 1) pv += __shfl_xor(pv, off, 64);
    __shared__ int wsp[4];
    if (lane == 0) wsp[wave] = pv;
    __syncthreads();
    int base = wsp[0] + wsp[1] + wsp[2] + wsp[3];

    int i = limit + t;
    int v = (i < N) ? deg[i] : 0;
    int inc = v;
    #pragma unroll
    for (int off = 1; off < 64; off <<= 1) {
        int u = __shfl_up(inc, off, 64);
        if (lane >= off) inc += u;
    }
    __shared__ int wsum[4];
    if (lane == 63) wsum[wave] = inc;
    __syncthreads();
    int woff = base;
    for (int w = 0; w < wave; ++w) woff += wsum[w];
    int excl = inc - v + woff;
    if (i < N) rowstart[i] = excl;
    if (i == N - 1) rowstart[N] = excl + v;
}

// ---------------- mega: gemm1 (BM=128, 8 waves, fused alpha) + edge scatter ------
__global__ __launch_bounds__(512) void mega1_k(
        const float* __restrict__ x, const ushort_t* __restrict__ Bt,
        ushort_t* __restrict__ Cb, const float* __restrict__ a_src,
        const float* __restrict__ a_dst, float* __restrict__ os,
        float* __restrict__ od, int M, int NG1,
        const int* __restrict__ ei, int E, int N,
        const int* __restrict__ rowstart, int* __restrict__ cursor,
        int* __restrict__ srcs) {
    __shared__ ushort_t Alds[128][40];
    __shared__ ushort_t Blds[256][40];
    const int tid = threadIdx.x;

    if (blockIdx.x >= NG1) {
        // ---- scatter path (512 edges/block) ----
        int e = (blockIdx.x - NG1) * 512 + tid;
        int T = E + N;
        if (e < T) {
            int s, d;
            if (e < E) { s = ei[e]; d = ei[E + e]; } else { s = e - E; d = s; }
            int p = atomicAdd(&cursor[d], 1);
            srcs[rowstart[d] + p] = s;
        }
        return;
    }

    // ---- gemm1: 128 rows x 256 cols, 8 waves = 2 row-halves x 4 head-quadrants ----
    const int bm = blockIdx.x * 128;
    const int w = tid >> 6;          // 0..7
    const int l = tid & 63;
    const int lr = l >> 4;
    const int lc = l & 15;
    const int rh = w >> 2;           // row half 0/1
    const int head = w & 3;          // col quadrant == head
    const int row0 = rh * 64;
    const int col0 = head * 64;

    f32x4 acc[4][4] = {};

    for (int kk = 0; kk < 4; ++kk) {
        __syncthreads();
        {
            // A: 128 rows x 4 parts = 512 items, one per thread
            int row = tid >> 2, part = tid & 3;
            int gm = bm + row;
            bf16x8 v = {0, 0, 0, 0, 0, 0, 0, 0};
            if (gm < M) {
                const float* ap = x + (size_t)gm * 128 + kk * 32 + part * 8;
                float4 v0 = *(const float4*)ap;
                float4 v1 = *(const float4*)(ap + 4);
                v[0] = (short)f2b(v0.x); v[1] = (short)f2b(v0.y);
                v[2] = (short)f2b(v0.z); v[3] = (short)f2b(v0.w);
                v[4] = (short)f2b(v1.x); v[5] = (short)f2b(v1.y);
                v[6] = (short)f2b(v1.z); v[7] = (short)f2b(v1.w);
            }
            *(bf16x8*)&Alds[row][part * 8] = v;
        }
        #pragma unroll
        for (int it = 0; it < 2; ++it) {
            // B: 256 cols x 4 parts = 1024 items / 512 threads
            int u = tid + it * 512;
            int col = u >> 2, part = u & 3;
            *(bf16x8*)&Blds[col][part * 8] =
                *(const bf16x8*)&Bt[(size_t)col * 128 + kk * 32 + part * 8];
        }
        __syncthreads();

        bf16x8 af[4], bfr[4];
        #pragma unroll
        for (int fr = 0; fr < 4; ++fr)
            af[fr] = *(const bf16x8*)&Alds[row0 + fr * 16 + lc][lr * 8];
        #pragma unroll
        for (int fc = 0; fc < 4; ++fc)
            bfr[fc] = *(const bf16x8*)&Blds[col0 + fc * 16 + lc][lr * 8];
        #pragma unroll
        for (int fr = 0; fr < 4; ++fr)
            #pragma unroll
            for (int fc = 0; fc < 4; ++fc)
                acc[fr][fc] = __builtin_amdgcn_mfma_f32_16x16x32_bf16(
                    af[fr], bfr[fc], acc[fr][fc], 0, 0, 0);
    }

    #pragma unroll
    for (int fr = 0; fr < 4; ++fr)
        #pragma unroll
        for (int r = 0; r < 4; ++r) {
            int gm = bm + row0 + fr * 16 + lr * 4 + r;
            if (gm >= M) continue;
            #pragma unroll
            for (int fc = 0; fc < 4; ++fc)
                Cb[(size_t)gm * 256 + col0 + fc * 16 + lc] = f2b(acc[fr][fc][r]);
        }

    {
        const float* __restrict__ asv = a_src + head * 64;
        const float* __restrict__ adv = a_dst + head * 64;
        #pragma unroll
        for (int fr = 0; fr < 4; ++fr)
            #pragma unroll
            for (int r = 0; r < 4; ++r) {
                float ps = 0.f, pd = 0.f;
                #pragma unroll
                for (int fc = 0; fc < 4; ++fc) {
                    float av = acc[fr][fc][r];
                    ps = fmaf(av, asv[fc * 16 + lc], ps);
                    pd = fmaf(av, adv[fc * 16 + lc], pd);
                }
                #pragma unroll
                for (int off = 1; off < 16; off <<= 1) {
                    ps += __shfl_xor(ps, off, 64);
                    pd += __shfl_xor(pd, off, 64);
                }
                int gm = bm + row0 + fr * 16 + lr * 4 + r;
                if (lc == 0 && gm < M) {
                    os[(size_t)gm * 4 + head] = ps;
                    od[(size_t)gm * 4 + head] = pd;
                }
            }
    }
}

// ---------------- MFMA GEMM (layer 2) with fused alpha epilogue ----------------
template<int WM, int WN, int K, bool B_WHOLE, int AH>
__global__ __launch_bounds__(WM * WN * 64) void gemm_mfma(
        const ushort_t* __restrict__ Ap, const ushort_t* __restrict__ Bt,
        ushort_t* __restrict__ Cb, const float* __restrict__ a_src,
        const float* __restrict__ a_dst, float* __restrict__ os,
        float* __restrict__ od, int M) {
    constexpr int T = WM * WN * 64;
    constexpr int BM = WM * 64;
    constexpr int BN = WN * 64;
    constexpr int BSTR = B_WHOLE ? (K + 8) : 40;

    __shared__ ushort_t Alds[BM][40];
    __shared__ ushort_t Blds[BN][BSTR];

    const int tid = threadIdx.x;
    const int bm = blockIdx.x * BM;
    const int w = tid >> 6;
    const int l = tid & 63;
    const int lr = l >> 4;
    const int lc = l & 15;
    const int row0 = (WM == 1) ? 0 : w * 64;
    const int col0 = (WN == 1) ? 0 : w * 64;

    f32x4 acc[4][4] = {};

    if (B_WHOLE) {
        constexpr int UPR = K / 8;
        for (int u = tid; u < BN * UPR; u += T) {
            int row = u / UPR, j = u % UPR;
            *(bf16x8*)&Blds[row][j * 8] = *(const bf16x8*)&Bt[(size_t)row * K + j * 8];
        }
    }

    for (int kk = 0; kk < K / 32; ++kk) {
        __syncthreads();
        for (int u = tid; u < BM * 4; u += T) {
            int row = u >> 2, part = u & 3;
            int gm = bm + row;
            bf16x8 v = {0, 0, 0, 0, 0, 0, 0, 0};
            if (gm < M)
                v = *(const bf16x8*)(Ap + (size_t)gm * K + kk * 32 + part * 8);
            *(bf16x8*)&Alds[row][part * 8] = v;
        }
        if (!B_WHOLE) {
            for (int u = tid; u < BN * 4; u += T) {
                int col = u >> 2, part = u & 3;
                *(bf16x8*)&Blds[col][part * 8] =
                    *(const bf16x8*)&Bt[(size_t)col * K + kk * 32 + part * 8];
            }
        }
        __syncthreads();

        const int koff = B_WHOLE ? kk * 32 : 0;
        bf16x8 af[4], bfr[4];
        #pragma unroll
        for (int fr = 0; fr < 4; ++fr)
            af[fr] = *(const bf16x8*)&Alds[row0 + fr * 16 + lc][lr * 8];
        #pragma unroll
        for (int fc = 0; fc < 4; ++fc)
            bfr[fc] = *(const bf16x8*)&Blds[col0 + fc * 16 + lc][koff + lr * 8];
        #pragma unroll
        for (int fr = 0; fr < 4; ++fr)
            #pragma unroll
            for (int fc = 0; fc < 4; ++fc)
                acc[fr][fc] = __builtin_amdgcn_mfma_f32_16x16x32_bf16(
                    af[fr], bfr[fc], acc[fr][fc], 0, 0, 0);
    }

    #pragma unroll
    for (int fr = 0; fr < 4; ++fr)
        #pragma unroll
        for (int r = 0; r < 4; ++r) {
            int gm = bm + row0 + fr * 16 + lr * 4 + r;
            if (gm >= M) continue;
            #pragma unroll
            for (int fc = 0; fc < 4; ++fc)
                Cb[(size_t)gm * BN + col0 + fc * 16 + lc] = f2b(acc[fr][fc][r]);
        }

    if (AH > 0) {
        const int head = (WN > 1) ? w : 0;
        const float* __restrict__ asv = a_src + head * 64;
        const float* __restrict__ adv = a_dst + head * 64;
        #pragma unroll
        for (int fr = 0; fr < 4; ++fr)
            #pragma unroll
            for (int r = 0; r < 4; ++r) {
                float ps = 0.f, pd = 0.f;
                #pragma unroll
                for (int fc = 0; fc < 4; ++fc) {
                    float av = acc[fr][fc][r];
                    ps = fmaf(av, asv[fc * 16 + lc], ps);
                    pd = fmaf(av, adv[fc * 16 + lc], pd);
                }
                #pragma unroll
                for (int off = 1; off < 16; off <<= 1) {
                    ps += __shfl_xor(ps, off, 64);
                    pd += __shfl_xor(pd, off, 64);
                }
                int gm = bm + row0 + fr * 16 + lr * 4 + r;
                if (lc == 0 && gm < M) {
                    os[(size_t)gm * AH + head] = ps;
                    od[(size_t)gm * AH + head] = pd;
                }
            }
    }
}

// ---------------- GAT aggregation, H=4: one wave per destination ----------------
#define MAXD 128
__global__ __launch_bounds__(256) void gat_agg4(const ushort_t* __restrict__ hb,
        const int* __restrict__ rowstart, const int* __restrict__ srcs,
        const float* __restrict__ as, const float* __restrict__ ad,
        const float* __restrict__ bias, ushort_t* __restrict__ outb, int N) {
    __shared__ int ssrc_s[4][MAXD];
    __shared__ float sw_s[4][MAXD][4];
    __shared__ float hstat_s[4][2][4];
    const int wave = threadIdx.x >> 6;
    const int lane = threadIdx.x & 63;
    int d = blockIdx.x * 4 + wave;
    if (d >= N) return;
    int* ssrc = ssrc_s[wave];
    float (*sw)[4] = sw_s[wave];
    int beg = rowstart[d];
    int deg = rowstart[d + 1] - beg;
    int dcap = deg < MAXD ? deg : MAXD;
    for (int i = lane; i < dcap; i += 64) ssrc[i] = srcs[beg + i];

    const int isub = lane >> 2;
    const int hd = lane & 3;
    float adv = ad[d * 4 + hd];
    float vmax = -INFINITY;
    for (int e0 = 0; e0 < deg; e0 += 16) {
        int e = e0 + isub;
        if (e < deg) {
            int s = (e < MAXD) ? ssrc[e] : srcs[beg + e];
            float v = as[s * 4 + hd] + adv;
            v = v > 0.f ? v : 0.2f * v;
            if (e < MAXD) sw[e][hd] = v;
            vmax = fmaxf(vmax, v);
        }
    }
    #pragma unroll
    for (int off = 4; off < 64; off <<= 1) vmax = fmaxf(vmax, __shfl_xor(vmax, off, 64));
    float dsum = 0.f;
    for (int e0 = 0; e0 < deg; e0 += 16) {
        int e = e0 + isub;
        if (e < deg) {
            float v;
            if (e < MAXD) v = sw[e][hd];
            else {
                int s = srcs[beg + e];
                v = as[s * 4 + hd] + adv;
                v = v > 0.f ? v : 0.2f * v;
            }
            float ex = __expf(v - vmax);
            if (e < MAXD) sw[e][hd] = ex;
            dsum += ex;
        }
    }
    #pragma unroll
    for (int off = 4; off < 64; off <<= 1) dsum += __shfl_xor(dsum, off, 64);
    float rden = 1.f / (dsum + 1e-16f);
    for (int e0 = 0; e0 < dcap; e0 += 16) {
        int e = e0 + isub;
        if (e < dcap) sw[e][hd] *= rden;
    }
    if (deg > MAXD && isub == 0) {
        hstat_s[wave][0][hd] = vmax;
        hstat_s[wave][1][hd] = rden;
    }

    const int hd2 = lane >> 4;
    const ushort_t* __restrict__ hrow = hb + (size_t)(lane * 4);
    float a0 = 0.f, a1 = 0.f, a2 = 0.f, a3 = 0.f;
    int e = 0;
    for (; e + 4 <= dcap; e += 4) {
        int s0 = __builtin_amdgcn_readfirstlane(ssrc[e]);
        int s1 = __builtin_amdgcn_readfirstlane(ssrc[e + 1]);
        int s2 = __builtin_amdgcn_readfirstlane(ssrc[e + 2]);
        int s3 = __builtin_amdgcn_readfirstlane(ssrc[e + 3]);
        ushort4 g0 = *(const ushort4*)(hrow + (size_t)s0 * 256);
        ushort4 g1 = *(const ushort4*)(hrow + (size_t)s1 * 256);
        ushort4 g2 = *(const ushort4*)(hrow + (size_t)s2 * 256);
        ushort4 g3 = *(const ushort4*)(hrow + (size_t)s3 * 256);
        float w0 = sw[e][hd2], w1 = sw[e + 1][hd2];
        float w2 = sw[e + 2][hd2], w3 = sw[e + 3][hd2];
        a0 = fmaf(b2f(g0.x), w0, a0); a1 = fmaf(b2f(g0.y), w0, a1);
        a2 = fmaf(b2f(g0.z), w0, a2); a3 = fmaf(b2f(g0.w), w0, a3);
        a0 = fmaf(b2f(g1.x), w1, a0); a1 = fmaf(b2f(g1.y), w1, a1);
        a2 = fmaf(b2f(g1.z), w1, a2); a3 = fmaf(b2f(g1.w), w1, a3);
        a0 = fmaf(b2f(g2.x), w2, a0); a1 = fmaf(b2f(g2.y), w2, a1);
        a2 = fmaf(b2f(g2.z), w2, a2); a3 = fmaf(b2f(g2.w), w2, a3);
        a0 = fmaf(b2f(g3.x), w3, a0); a1 = fmaf(b2f(g3.y), w3, a1);
        a2 = fmaf(b2f(g3.z), w3, a2); a3 = fmaf(b2f(g3.w), w3, a3);
    }
    for (; e < dcap; ++e) {
        int s = __builtin_amdgcn_readfirstlane(ssrc[e]);
        float w = sw[e][hd2];
        ushort4 g = *(const ushort4*)(hrow + (size_t)s * 256);
        a0 = fmaf(b2f(g.x), w, a0); a1 = fmaf(b2f(g.y), w, a1);
        a2 = fmaf(b2f(g.z), w, a2); a3 = fmaf(b2f(g.w), w, a3);
    }
    if (deg > MAXD) {
        float vm2 = hstat_s[wave][0][hd2];
        float rd2 = hstat_s[wave][1][hd2];
        float adv2 = ad[d * 4 + hd2];
        for (int j = MAXD; j < deg; ++j) {
            int s = srcs[beg + j];
            float v = as[s * 4 + hd2] + adv2;
            v = v > 0.f ? v : 0.2f * v;
            float w = __expf(v - vm2) * rd2;
            ushort4 g = *(const ushort4*)(hrow + (size_t)s * 256);
            a0 = fmaf(b2f(g.x), w, a0); a1 = fmaf(b2f(g.y), w, a1);
            a2 = fmaf(b2f(g.z), w, a2); a3 = fmaf(b2f(g.w), w, a3);
        }
    }
    int cb = lane * 4;
    ushort4 ov;
    ov.x = f2b(fmaxf(a0 + bias[cb + 0], 0.f));
    ov.y = f2b(fmaxf(a1 + bias[cb + 1], 0.f));
    ov.z = f2b(fmaxf(a2 + bias[cb + 2], 0.f));
    ov.w = f2b(fmaxf(a3 + bias[cb + 3], 0.f));
    *(ushort4*)&outb[(size_t)d * 256 + cb] = ov;
}

// ---------------- GAT aggregation H=1 with fused mean-pool into d_out ----------
__global__ __launch_bounds__(256) void gat_agg1(const ushort_t* __restrict__ hb,
        const int* __restrict__ rowstart, const int* __restrict__ srcs,
        const float* __restrict__ as, const float* __restrict__ ad,
        const float* __restrict__ bias, const int* __restrict__ batch,
        const int* __restrict__ cnt_i, float* __restrict__ outp, int N) {
    __shared__ int ssrc_s[4][MAXD];
    __shared__ float sw_s[4][MAXD];
    __shared__ float prow[4][64];
    __shared__ int gws[4];
    const int wave = threadIdx.x >> 6;
    const int lane = threadIdx.x & 63;
    int d = blockIdx.x * 4 + wave;
    bool active = d < N;
    if (active) {
        int* ssrc = ssrc_s[wave];
        float* sw = sw_s[wave];
        int beg = rowstart[d];
        int deg = rowstart[d + 1] - beg;
        int dcap = deg < MAXD ? deg : MAXD;
        for (int i = lane; i < dcap; i += 64) ssrc[i] = srcs[beg + i];

        float adv = ad[d];
        float vmax = -INFINITY;
        for (int e0 = 0; e0 < deg; e0 += 64) {
            int e = e0 + lane;
            if (e < deg) {
                int s = (e < MAXD) ? ssrc[e] : srcs[beg + e];
                float v = as[s] + adv;
                v = v > 0.f ? v : 0.2f * v;
                if (e < MAXD) sw[e] = v;
                vmax = fmaxf(vmax, v);
            }
        }
        #pragma unroll
        for (int off = 1; off < 64; off <<= 1) vmax = fmaxf(vmax, __shfl_xor(vmax, off, 64));
        float dsum = 0.f;
        for (int e0 = 0; e0 < deg; e0 += 64) {
            int e = e0 + lane;
            if (e < deg) {
                float v;
                if (e < MAXD) v = sw[e];
                else {
                    int s = srcs[beg + e];
                    v = as[s] + adv;
                    v = v > 0.f ? v : 0.2f * v;
                }
                float ex = __expf(v - vmax);
                if (e < MAXD) sw[e] = ex;
                dsum += ex;
            }
        }
        #pragma unroll
        for (int off = 1; off < 64; off <<= 1) dsum += __shfl_xor(dsum, off, 64);
        float rden = 1.f / (dsum + 1e-16f);
        for (int e0 = 0; e0 < dcap; e0 += 64) {
            int e = e0 + lane;
            if (e < dcap) sw[e] *= rden;
        }

        const int esub = lane >> 4;
        const int cg = lane & 15;
        const ushort_t* __restrict__ hrow = hb + (size_t)(cg * 4);
        float a0 = 0.f, a1 = 0.f, a2 = 0.f, a3 = 0.f;
        int e0 = 0;
        for (; e0 + 8 <= dcap; e0 += 8) {
            int eA = e0 + esub, eB = e0 + esub + 4;
            int sA = ssrc[eA], sB = ssrc[eB];
            float wA = sw[eA], wB = sw[eB];
            ushort4 gA = *(const ushort4*)(hrow + (size_t)sA * 64);
            ushort4 gB = *(const ushort4*)(hrow + (size_t)sB * 64);
            a0 = fmaf(b2f(gA.x), wA, a0); a1 = fmaf(b2f(gA.y), wA, a1);
            a2 = fmaf(b2f(gA.z), wA, a2); a3 = fmaf(b2f(gA.w), wA, a3);
            a0 = fmaf(b2f(gB.x), wB, a0); a1 = fmaf(b2f(gB.y), wB, a1);
            a2 = fmaf(b2f(gB.z), wB, a2); a3 = fmaf(b2f(gB.w), wB, a3);
        }
        for (; e0 < dcap; e0 += 4) {
            int e = e0 + esub;
            if (e < dcap) {
                int s = ssrc[e];
                float w = sw[e];
                ushort4 g = *(const ushort4*)(hrow + (size_t)s * 64);
                a0 = fmaf(b2f(g.x), w, a0); a1 = fmaf(b2f(g.y), w, a1);
                a2 = fmaf(b2f(g.z), w, a2); a3 = fmaf(b2f(g.w), w, a3);
            }
        }
        for (int j = MAXD + esub; j < deg; j += 4) {
            int s = srcs[beg + j];
            float v = as[s] + adv;
            v = v > 0.f ? v : 0.2f * v;
            float w = __expf(v - vmax) * rden;
            ushort4 g = *(const ushort4*)(hrow + (size_t)s * 64);
            a0 = fmaf(b2f(g.x), w, a0); a1 = fmaf(b2f(g.y), w, a1);
            a2 = fmaf(b2f(g.z), w, a2); a3 = fmaf(b2f(g.w), w, a3);
        }
        a0 += __shfl_xor(a0, 16, 64); a0 += __shfl_xor(a0, 32, 64);
        a1 += __shfl_xor(a1, 16, 64); a1 += __shfl_xor(a1, 32, 64);
        a2 += __shfl_xor(a2, 16, 64); a2 += __shfl_xor(a2, 32, 64);
        a3 += __shfl_xor(a3, 16, 64); a3 += __shfl_xor(a3, 32, 64);
        int g = batch[d];
        if (esub == 0) {
            float cntf = fmaxf((float)cnt_i[g], 1.f);
            float rc = 1.f / cntf;
            int cb = cg * 4;
            float4 o;
            o.x = (a0 + bias[cb + 0]) * rc;
            o.y = (a1 + bias[cb + 1]) * rc;
            o.z = (a2 + bias[cb + 2]) * rc;
            o.w = (a3 + bias[cb + 3]) * rc;
            *(float4*)&prow[wave][cb] = o;
        }
        if (lane == 0) gws[wave] = g;
    } else {
        if (lane == 0) gws[wave] = -1;
    }
    __syncthreads();
    if (threadIdx.x < 64) {
        int t = threadIdx.x;
        int g0 = gws[0];
        if (g0 >= 0 && gws[1] == g0 && gws[2] == g0 && gws[3] == g0) {
            atomicAdd(&outp[g0 * 64 + t],
                      prow[0][t] + prow[1][t] + prow[2][t] + prow[3][t]);
        } else {
            #pragma unroll
            for (int w2 = 0; w2 < 4; ++w2)
                if (gws[w2] >= 0) atomicAdd(&outp[gws[w2] * 64 + t], prow[w2][t]);
        }
    }
}

// ---------------- launch ----------------

extern "C" void kernel_launch(void* const* d_in, const int* in_sizes, int n_in,
                              void* d_out, int out_size, void* d_ws, size_t ws_size,
                              hipStream_t stream) {
    const float* x      = (const float*)d_in[0];
    const int*   ei     = (const int*)d_in[1];
    const int*   batch  = (const int*)d_in[2];
    const float* W1     = (const float*)d_in[3];
    const float* a_src1 = (const float*)d_in[4];
    const float* a_dst1 = (const float*)d_in[5];
    const float* b1     = (const float*)d_in[6];
    const float* W2     = (const float*)d_in[7];
    const float* a_src2 = (const float*)d_in[8];
    const float* a_dst2 = (const float*)d_in[9];
    const float* b2     = (const float*)d_in[10];
    float* out = (float*)d_out;

    const int N = in_sizes[0] / 128;    // 50000
    const int E = in_sizes[1] / 2;      // 800000
    const int F1 = 256;
    const int F2 = 64;
    const int T = E + N;
    const int NB = (N + 255) / 256;     // scan/hist blocks (196)
    const int NCB = (T + 255) / 256;    // count blocks, 256 threads (3321)
    const int NSB = (T + 511) / 512;    // scatter blocks, 512 threads (1661)
    const int NG1 = (N + 127) / 128;    // gemm1 blocks (391)

    // ---- workspace layout (float units) ----
    float* ws = (float*)d_ws;
    size_t o = 0;
    ushort_t* h1b   = (ushort_t*)(ws + o); o += (size_t)N * F1 / 2;
    ushort_t* out1b = (ushort_t*)(ws + o); o += (size_t)N * F1 / 2;
    ushort_t* h2b   = (ushort_t*)(ws + o); o += (size_t)N * F2 / 2;
    float* asrc1 = ws + o; o += (size_t)N * 4;
    float* adst1 = ws + o; o += (size_t)N * 4;
    float* asrc2 = ws + o; o += (size_t)N;
    float* adst2 = ws + o; o += (size_t)N;
    ushort_t* W1t = (ushort_t*)(ws + o); o += 256 * 128 / 2;
    ushort_t* W2t = (ushort_t*)(ws + o); o += 64 * 256 / 2;
    int* ib = (int*)(ws + o);
    size_t io = 0;
    int* deg      = ib + io; io += N;
    int* cursor   = ib + io; io += N;
    int* cnt_i    = ib + io; io += 32;
    int* rowstart = ib + io; io += N + 1;
    int* srcs     = ib + io; io += T;
    (void)ws_size; (void)n_in; (void)out_size;

    // ---- zero counters; prep (transposes + hist + zero out + degree count) ----
    fill_i32<<<256, 256, 0, stream>>>(deg, 0, 2L * N + 32);
    prep_k<<<385 + NB + NCB, 256, 0, stream>>>(W1, W2, W1t, W2t, batch, cnt_i, out,
                                               ei, deg, N, E, NB);

    // ---- fused CSR scan (one dispatch) ----
    scan_k<<<NB, 256, 0, stream>>>(deg, rowstart, N);

    // ---- gemm1 (BM=128) + scatter in one dispatch ----
    mega1_k<<<NG1 + NSB, 512, 0, stream>>>(x, W1t, h1b, a_src1, a_dst1,
                                           asrc1, adst1, N, NG1,
                                           ei, E, N, rowstart, cursor, srcs);

    // ---- layer 1 aggregation ----
    gat_agg4<<<(N + 3) / 4, 256, 0, stream>>>(h1b, rowstart, srcs, asrc1, adst1, b1, out1b, N);

    // ---- layer 2 (+ fused mean pool) ----
    gemm_mfma<2, 1, 256, true, 1><<<(N + 127) / 128, 128, 0, stream>>>(
        out1b, W2t, h2b, a_src2, a_dst2, asrc2, adst2, N);
    gat_agg1<<<(N + 3) / 4, 256, 0, stream>>>(h2b, rowstart, srcs, asrc2, adst2, b2,
                                              batch, cnt_i, out, N);
}

// Round 13
// 237.078 us; speedup vs baseline: 1.0706x; 1.0706x over previous
//
#include <hip/hip_runtime.h>
#include <cmath>

#define HID 64
typedef unsigned short ushort_t;
typedef __attribute__((ext_vector_type(8))) short bf16x8;
typedef __attribute__((ext_vector_type(4))) float f32x4;

__device__ inline ushort_t f2b(float f) {
    unsigned u = __float_as_uint(f);
    unsigned r = (u + 0x7fffu + ((u >> 16) & 1u)) >> 16;
    return (ushort_t)r;
}
__device__ inline float b2f(ushort_t b) { return __uint_as_float(((unsigned)b) << 16); }

// ---------------- fills ----------------

__global__ void fill_i32(int* __restrict__ p, int v, long n) {
    long i = (long)blockIdx.x * blockDim.x + threadIdx.x;
    long stride = (long)gridDim.x * blockDim.x;
    for (; i < n; i += stride) p[i] = v;
}

// ---------------- prep: transposes + zero d_out + batch hist + edge count ----------
__global__ __launch_bounds__(256) void prep_k(const float* __restrict__ W1,
                                              const float* __restrict__ W2,
                                              ushort_t* __restrict__ W1t,
                                              ushort_t* __restrict__ W2t,
                                              const int* __restrict__ batch,
                                              int* __restrict__ cnt_i,
                                              float* __restrict__ outp,
                                              const int* __restrict__ ei,
                                              int* __restrict__ deg,
                                              int N, int E, int NHB) {
    int b = blockIdx.x;
    int t = threadIdx.x;
    if (b < 128) {
        W1t[(size_t)t * 128 + b] = f2b(W1[(size_t)b * 256 + t]);
    } else if (b < 384) {
        int k = b - 128;
        if (t < 64) W2t[(size_t)t * 256 + k] = f2b(W2[(size_t)k * 64 + t]);
    } else if (b == 384) {
        int i = t * 8;
        #pragma unroll
        for (int j = 0; j < 8; ++j) outp[i + j] = 0.f;
    } else if (b < 385 + NHB) {
        __shared__ int lh[32];
        if (t < 32) lh[t] = 0;
        __syncthreads();
        int i = (b - 385) * 256 + t;
        if (i < N) atomicAdd(&lh[batch[i]], 1);
        __syncthreads();
        if (t < 32 && lh[t] > 0) atomicAdd(&cnt_i[t], lh[t]);
    } else {
        int e = (b - 385 - NHB) * 256 + t;
        int T = E + N;
        if (e < T) {
            int d = (e < E) ? ei[E + e] : (e - E);
            atomicAdd(&deg[d], 1);
        }
    }
}

// ---------------- CSR scan ----------------

__global__ __launch_bounds__(256) void scan1_k(const int* __restrict__ deg,
                                               int* __restrict__ bsum, int N) {
    int i = blockIdx.x * 256 + threadIdx.x;
    int v = (i < N) ? deg[i] : 0;
    #pragma unroll
    for (int off = 32; off > 0; off >>= 1) v += __shfl_xor(v, off, 64);
    __shared__ int ws[4];
    if ((threadIdx.x & 63) == 0) ws[threadIdx.x >> 6] = v;
    __syncthreads();
    if (threadIdx.x == 0) bsum[blockIdx.x] = ws[0] + ws[1] + ws[2] + ws[3];
}

__global__ __launch_bounds__(256) void scan3_k(const int* __restrict__ deg,
                                               const int* __restrict__ bsum,
                                               int* __restrict__ rowstart, int N, int NB) {
    int t = threadIdx.x;
    int lane = t & 63, wave = t >> 6;
    int pv = (t < NB && t < (int)blockIdx.x) ? bsum[t] : 0;
    #pragma unroll
    for (int off = 32; off > 0; off >>= 1) pv += __shfl_xor(pv, off, 64);
    __shared__ int wsp[4];
    if (lane == 0) wsp[wave] = pv;
    __syncthreads();
    int base = wsp[0] + wsp[1] + wsp[2] + wsp[3];

    int i = blockIdx.x * 256 + t;
    int v = (i < N) ? deg[i] : 0;
    int inc = v;
    #pragma unroll
    for (int off = 1; off < 64; off <<= 1) {
        int u = __shfl_up(inc, off, 64);
        if (lane >= off) inc += u;
    }
    __shared__ int wsum[4];
    if (lane == 63) wsum[wave] = inc;
    __syncthreads();
    int woff = base;
    for (int w = 0; w < wave; ++w) woff += wsum[w];
    int excl = inc - v + woff;
    if (i < N) rowstart[i] = excl;
    if (i == N - 1) rowstart[N] = excl + v;
}

// ---------------- mega: gemm1 (MFMA, fused alpha) + edge scatter ----------------
__global__ __launch_bounds__(256) void mega1_k(
        const float* __restrict__ x, const ushort_t* __restrict__ Bt,
        ushort_t* __restrict__ Cb, const float* __restrict__ a_src,
        const float* __restrict__ a_dst, float* __restrict__ os,
        float* __restrict__ od, int M, int NG1,
        const int* __restrict__ ei, int E, int N,
        const int* __restrict__ rowstart, int* __restrict__ cursor,
        int* __restrict__ srcs) {
    __shared__ ushort_t Alds[64][40];
    __shared__ ushort_t Blds[256][40];
    const int tid = threadIdx.x;

    if (blockIdx.x >= NG1) {
        int e = (blockIdx.x - NG1) * 256 + tid;
        int T = E + N;
        if (e < T) {
            int s, d;
            if (e < E) { s = ei[e]; d = ei[E + e]; } else { s = e - E; d = s; }
            int p = atomicAdd(&cursor[d], 1);
            srcs[rowstart[d] + p] = s;
        }
        return;
    }

    const int bm = blockIdx.x * 64;
    const int w = tid >> 6;
    const int l = tid & 63;
    const int lr = l >> 4;
    const int lc = l & 15;
    const int col0 = w * 64;

    f32x4 acc[4][4] = {};

    for (int kk = 0; kk < 4; ++kk) {
        __syncthreads();
        {
            int row = tid >> 2, part = tid & 3;
            int gm = bm + row;
            bf16x8 v = {0, 0, 0, 0, 0, 0, 0, 0};
            if (gm < M) {
                const float* ap = x + (size_t)gm * 128 + kk * 32 + part * 8;
                float4 v0 = *(const float4*)ap;
                float4 v1 = *(const float4*)(ap + 4);
                v[0] = (short)f2b(v0.x); v[1] = (short)f2b(v0.y);
                v[2] = (short)f2b(v0.z); v[3] = (short)f2b(v0.w);
                v[4] = (short)f2b(v1.x); v[5] = (short)f2b(v1.y);
                v[6] = (short)f2b(v1.z); v[7] = (short)f2b(v1.w);
            }
            *(bf16x8*)&Alds[row][part * 8] = v;
        }
        #pragma unroll
        for (int it = 0; it < 4; ++it) {
            int u = tid + it * 256;
            int col = u >> 2, part = u & 3;
            *(bf16x8*)&Blds[col][part * 8] =
                *(const bf16x8*)&Bt[(size_t)col * 128 + kk * 32 + part * 8];
        }
        __syncthreads();

        bf16x8 af[4], bfr[4];
        #pragma unroll
        for (int fr = 0; fr < 4; ++fr)
            af[fr] = *(const bf16x8*)&Alds[fr * 16 + lc][lr * 8];
        #pragma unroll
        for (int fc = 0; fc < 4; ++fc)
            bfr[fc] = *(const bf16x8*)&Blds[col0 + fc * 16 + lc][lr * 8];
        #pragma unroll
        for (int fr = 0; fr < 4; ++fr)
            #pragma unroll
            for (int fc = 0; fc < 4; ++fc)
                acc[fr][fc] = __builtin_amdgcn_mfma_f32_16x16x32_bf16(
                    af[fr], bfr[fc], acc[fr][fc], 0, 0, 0);
    }

    #pragma unroll
    for (int fr = 0; fr < 4; ++fr)
        #pragma unroll
        for (int r = 0; r < 4; ++r) {
            int gm = bm + fr * 16 + lr * 4 + r;
            if (gm >= M) continue;
            #pragma unroll
            for (int fc = 0; fc < 4; ++fc)
                Cb[(size_t)gm * 256 + col0 + fc * 16 + lc] = f2b(acc[fr][fc][r]);
        }

    {
        const int head = w;
        const float* __restrict__ asv = a_src + head * 64;
        const float* __restrict__ adv = a_dst + head * 64;
        #pragma unroll
        for (int fr = 0; fr < 4; ++fr)
            #pragma unroll
            for (int r = 0; r < 4; ++r) {
                float ps = 0.f, pd = 0.f;
                #pragma unroll
                for (int fc = 0; fc < 4; ++fc) {
                    float av = acc[fr][fc][r];
                    ps = fmaf(av, asv[fc * 16 + lc], ps);
                    pd = fmaf(av, adv[fc * 16 + lc], pd);
                }
                #pragma unroll
                for (int off = 1; off < 16; off <<= 1) {
                    ps += __shfl_xor(ps, off, 64);
                    pd += __shfl_xor(pd, off, 64);
                }
                int gm = bm + fr * 16 + lr * 4 + r;
                if (lc == 0 && gm < M) {
                    os[(size_t)gm * 4 + head] = ps;
                    od[(size_t)gm * 4 + head] = pd;
                }
            }
    }
}

// ---------------- MFMA GEMM (layer 2) with fused alpha epilogue ----------------
template<int WM, int WN, int K, bool B_WHOLE, int AH>
__global__ __launch_bounds__(WM * WN * 64) void gemm_mfma(
        const ushort_t* __restrict__ Ap, const ushort_t* __restrict__ Bt,
        ushort_t* __restrict__ Cb, const float* __restrict__ a_src,
        const float* __restrict__ a_dst, float* __restrict__ os,
        float* __restrict__ od, int M) {
    constexpr int T = WM * WN * 64;
    constexpr int BM = WM * 64;
    constexpr int BN = WN * 64;
    constexpr int BSTR = B_WHOLE ? (K + 8) : 40;

    __shared__ ushort_t Alds[BM][40];
    __shared__ ushort_t Blds[BN][BSTR];

    const int tid = threadIdx.x;
    const int bm = blockIdx.x * BM;
    const int w = tid >> 6;
    const int l = tid & 63;
    const int lr = l >> 4;
    const int lc = l & 15;
    const int row0 = (WM == 1) ? 0 : w * 64;
    const int col0 = (WN == 1) ? 0 : w * 64;

    f32x4 acc[4][4] = {};

    if (B_WHOLE) {
        constexpr int UPR = K / 8;
        for (int u = tid; u < BN * UPR; u += T) {
            int row = u / UPR, j = u % UPR;
            *(bf16x8*)&Blds[row][j * 8] = *(const bf16x8*)&Bt[(size_t)row * K + j * 8];
        }
    }

    for (int kk = 0; kk < K / 32; ++kk) {
        __syncthreads();
        for (int u = tid; u < BM * 4; u += T) {
            int row = u >> 2, part = u & 3;
            int gm = bm + row;
            bf16x8 v = {0, 0, 0, 0, 0, 0, 0, 0};
            if (gm < M)
                v = *(const bf16x8*)(Ap + (size_t)gm * K + kk * 32 + part * 8);
            *(bf16x8*)&Alds[row][part * 8] = v;
        }
        if (!B_WHOLE) {
            for (int u = tid; u < BN * 4; u += T) {
                int col = u >> 2, part = u & 3;
                *(bf16x8*)&Blds[col][part * 8] =
                    *(const bf16x8*)&Bt[(size_t)col * K + kk * 32 + part * 8];
            }
        }
        __syncthreads();

        const int koff = B_WHOLE ? kk * 32 : 0;
        bf16x8 af[4], bfr[4];
        #pragma unroll
        for (int fr = 0; fr < 4; ++fr)
            af[fr] = *(const bf16x8*)&Alds[row0 + fr * 16 + lc][lr * 8];
        #pragma unroll
        for (int fc = 0; fc < 4; ++fc)
            bfr[fc] = *(const bf16x8*)&Blds[col0 + fc * 16 + lc][koff + lr * 8];
        #pragma unroll
        for (int fr = 0; fr < 4; ++fr)
            #pragma unroll
            for (int fc = 0; fc < 4; ++fc)
                acc[fr][fc] = __builtin_amdgcn_mfma_f32_16x16x32_bf16(
                    af[fr], bfr[fc], acc[fr][fc], 0, 0, 0);
    }

    #pragma unroll
    for (int fr = 0; fr < 4; ++fr)
        #pragma unroll
        for (int r = 0; r < 4; ++r) {
            int gm = bm + row0 + fr * 16 + lr * 4 + r;
            if (gm >= M) continue;
            #pragma unroll
            for (int fc = 0; fc < 4; ++fc)
                Cb[(size_t)gm * BN + col0 + fc * 16 + lc] = f2b(acc[fr][fc][r]);
        }

    if (AH > 0) {
        const int head = (WN > 1) ? w : 0;
        const float* __restrict__ asv = a_src + head * 64;
        const float* __restrict__ adv = a_dst + head * 64;
        #pragma unroll
        for (int fr = 0; fr < 4; ++fr)
            #pragma unroll
            for (int r = 0; r < 4; ++r) {
                float ps = 0.f, pd = 0.f;
                #pragma unroll
                for (int fc = 0; fc < 4; ++fc) {
                    float av = acc[fr][fc][r];
                    ps = fmaf(av, asv[fc * 16 + lc], ps);
                    pd = fmaf(av, adv[fc * 16 + lc], pd);
                }
                #pragma unroll
                for (int off = 1; off < 16; off <<= 1) {
                    ps += __shfl_xor(ps, off, 64);
                    pd += __shfl_xor(pd, off, 64);
                }
                int gm = bm + row0 + fr * 16 + lr * 4 + r;
                if (lc == 0 && gm < M) {
                    os[(size_t)gm * AH + head] = ps;
                    od[(size_t)gm * AH + head] = pd;
                }
            }
    }
}

// ---------------- GAT aggregation, H=4: one wave per destination ----------------
#define MAXD 128
__global__ __launch_bounds__(256) void gat_agg4(const ushort_t* __restrict__ hb,
        const int* __restrict__ rowstart, const int* __restrict__ srcs,
        const float* __restrict__ as, const float* __restrict__ ad,
        const float* __restrict__ bias, ushort_t* __restrict__ outb, int N) {
    __shared__ int ssrc_s[4][MAXD];
    __shared__ float sw_s[4][MAXD][4];
    __shared__ float hstat_s[4][2][4];
    const int wave = threadIdx.x >> 6;
    const int lane = threadIdx.x & 63;
    int d = blockIdx.x * 4 + wave;
    if (d >= N) return;
    int* ssrc = ssrc_s[wave];
    float (*sw)[4] = sw_s[wave];
    int beg = rowstart[d];
    int deg = rowstart[d + 1] - beg;
    int dcap = deg < MAXD ? deg : MAXD;
    for (int i = lane; i < dcap; i += 64) ssrc[i] = srcs[beg + i];

    const int isub = lane >> 2;
    const int hd = lane & 3;
    float adv = ad[d * 4 + hd];
    float vmax = -INFINITY;
    for (int e0 = 0; e0 < deg; e0 += 16) {
        int e = e0 + isub;
        if (e < deg) {
            int s = (e < MAXD) ? ssrc[e] : srcs[beg + e];
            float v = as[s * 4 + hd] + adv;
            v = v > 0.f ? v : 0.2f * v;
            if (e < MAXD) sw[e][hd] = v;
            vmax = fmaxf(vmax, v);
        }
    }
    #pragma unroll
    for (int off = 4; off < 64; off <<= 1) vmax = fmaxf(vmax, __shfl_xor(vmax, off, 64));
    float dsum = 0.f;
    for (int e0 = 0; e0 < deg; e0 += 16) {
        int e = e0 + isub;
        if (e < deg) {
            float v;
            if (e < MAXD) v = sw[e][hd];
            else {
                int s = srcs[beg + e];
                v = as[s * 4 + hd] + adv;
                v = v > 0.f ? v : 0.2f * v;
            }
            float ex = __expf(v - vmax);
            if (e < MAXD) sw[e][hd] = ex;
            dsum += ex;
        }
    }
    #pragma unroll
    for (int off = 4; off < 64; off <<= 1) dsum += __shfl_xor(dsum, off, 64);
    float rden = 1.f / (dsum + 1e-16f);
    for (int e0 = 0; e0 < dcap; e0 += 16) {
        int e = e0 + isub;
        if (e < dcap) sw[e][hd] *= rden;
    }
    if (deg > MAXD && isub == 0) {
        hstat_s[wave][0][hd] = vmax;
        hstat_s[wave][1][hd] = rden;
    }

    const int hd2 = lane >> 4;
    const ushort_t* __restrict__ hrow = hb + (size_t)(lane * 4);
    float a0 = 0.f, a1 = 0.f, a2 = 0.f, a3 = 0.f;
    int e = 0;
    for (; e + 4 <= dcap; e += 4) {
        int s0 = __builtin_amdgcn_readfirstlane(ssrc[e]);
        int s1 = __builtin_amdgcn_readfirstlane(ssrc[e + 1]);
        int s2 = __builtin_amdgcn_readfirstlane(ssrc[e + 2]);
        int s3 = __builtin_amdgcn_readfirstlane(ssrc[e + 3]);
        ushort4 g0 = *(const ushort4*)(hrow + (size_t)s0 * 256);
        ushort4 g1 = *(const ushort4*)(hrow + (size_t)s1 * 256);
        ushort4 g2 = *(const ushort4*)(hrow + (size_t)s2 * 256);
        ushort4 g3 = *(const ushort4*)(hrow + (size_t)s3 * 256);
        float w0 = sw[e][hd2], w1 = sw[e + 1][hd2];
        float w2 = sw[e + 2][hd2], w3 = sw[e + 3][hd2];
        a0 = fmaf(b2f(g0.x), w0, a0); a1 = fmaf(b2f(g0.y), w0, a1);
        a2 = fmaf(b2f(g0.z), w0, a2); a3 = fmaf(b2f(g0.w), w0, a3);
        a0 = fmaf(b2f(g1.x), w1, a0); a1 = fmaf(b2f(g1.y), w1, a1);
        a2 = fmaf(b2f(g1.z), w1, a2); a3 = fmaf(b2f(g1.w), w1, a3);
        a0 = fmaf(b2f(g2.x), w2, a0); a1 = fmaf(b2f(g2.y), w2, a1);
        a2 = fmaf(b2f(g2.z), w2, a2); a3 = fmaf(b2f(g2.w), w2, a3);
        a0 = fmaf(b2f(g3.x), w3, a0); a1 = fmaf(b2f(g3.y), w3, a1);
        a2 = fmaf(b2f(g3.z), w3, a2); a3 = fmaf(b2f(g3.w), w3, a3);
    }
    for (; e < dcap; ++e) {
        int s = __builtin_amdgcn_readfirstlane(ssrc[e]);
        float w = sw[e][hd2];
        ushort4 g = *(const ushort4*)(hrow + (size_t)s * 256);
        a0 = fmaf(b2f(g.x), w, a0); a1 = fmaf(b2f(g.y), w, a1);
        a2 = fmaf(b2f(g.z), w, a2); a3 = fmaf(b2f(g.w), w, a3);
    }
    if (deg > MAXD) {
        float vm2 = hstat_s[wave][0][hd2];
        float rd2 = hstat_s[wave][1][hd2];
        float adv2 = ad[d * 4 + hd2];
        for (int j = MAXD; j < deg; ++j) {
            int s = srcs[beg + j];
            float v = as[s * 4 + hd2] + adv2;
            v = v > 0.f ? v : 0.2f * v;
            float w = __expf(v - vm2) * rd2;
            ushort4 g = *(const ushort4*)(hrow + (size_t)s * 256);
            a0 = fmaf(b2f(g.x), w, a0); a1 = fmaf(b2f(g.y), w, a1);
            a2 = fmaf(b2f(g.z), w, a2); a3 = fmaf(b2f(g.w), w, a3);
        }
    }
    int cb = lane * 4;
    ushort4 ov;
    ov.x = f2b(fmaxf(a0 + bias[cb + 0], 0.f));
    ov.y = f2b(fmaxf(a1 + bias[cb + 1], 0.f));
    ov.z = f2b(fmaxf(a2 + bias[cb + 2], 0.f));
    ov.w = f2b(fmaxf(a3 + bias[cb + 3], 0.f));
    *(ushort4*)&outb[(size_t)d * 256 + cb] = ov;
}

// ---------------- GAT aggregation H=1 with fused mean-pool into d_out ----------
__global__ __launch_bounds__(256) void gat_agg1(const ushort_t* __restrict__ hb,
        const int* __restrict__ rowstart, const int* __restrict__ srcs,
        const float* __restrict__ as, const float* __restrict__ ad,
        const float* __restrict__ bias, const int* __restrict__ batch,
        const int* __restrict__ cnt_i, float* __restrict__ outp, int N) {
    __shared__ int ssrc_s[4][MAXD];
    __shared__ float sw_s[4][MAXD];
    __shared__ float prow[4][64];
    __shared__ int gws[4];
    const int wave = threadIdx.x >> 6;
    const int lane = threadIdx.x & 63;
    int d = blockIdx.x * 4 + wave;
    bool active = d < N;
    if (active) {
        int* ssrc = ssrc_s[wave];
        float* sw = sw_s[wave];
        int beg = rowstart[d];
        int deg = rowstart[d + 1] - beg;
        int dcap = deg < MAXD ? deg : MAXD;
        for (int i = lane; i < dcap; i += 64) ssrc[i] = srcs[beg + i];

        float adv = ad[d];
        float vmax = -INFINITY;
        for (int e0 = 0; e0 < deg; e0 += 64) {
            int e = e0 + lane;
            if (e < deg) {
                int s = (e < MAXD) ? ssrc[e] : srcs[beg + e];
                float v = as[s] + adv;
                v = v > 0.f ? v : 0.2f * v;
                if (e < MAXD) sw[e] = v;
                vmax = fmaxf(vmax, v);
            }
        }
        #pragma unroll
        for (int off = 1; off < 64; off <<= 1) vmax = fmaxf(vmax, __shfl_xor(vmax, off, 64));
        float dsum = 0.f;
        for (int e0 = 0; e0 < deg; e0 += 64) {
            int e = e0 + lane;
            if (e < deg) {
                float v;
                if (e < MAXD) v = sw[e];
                else {
                    int s = srcs[beg + e];
                    v = as[s] + adv;
                    v = v > 0.f ? v : 0.2f * v;
                }
                float ex = __expf(v - vmax);
                if (e < MAXD) sw[e] = ex;
                dsum += ex;
            }
        }
        #pragma unroll
        for (int off = 1; off < 64; off <<= 1) dsum += __shfl_xor(dsum, off, 64);
        float rden = 1.f / (dsum + 1e-16f);
        for (int e0 = 0; e0 < dcap; e0 += 64) {
            int e = e0 + lane;
            if (e < dcap) sw[e] *= rden;
        }

        const int esub = lane >> 4;
        const int cg = lane & 15;
        const ushort_t* __restrict__ hrow = hb + (size_t)(cg * 4);
        float a0 = 0.f, a1 = 0.f, a2 = 0.f, a3 = 0.f;
        int e0 = 0;
        for (; e0 + 8 <= dcap; e0 += 8) {
            int eA = e0 + esub, eB = e0 + esub + 4;
            int sA = ssrc[eA], sB = ssrc[eB];
            float wA = sw[eA], wB = sw[eB];
            ushort4 gA = *(const ushort4*)(hrow + (size_t)sA * 64);
            ushort4 gB = *(const ushort4*)(hrow + (size_t)sB * 64);
            a0 = fmaf(b2f(gA.x), wA, a0); a1 = fmaf(b2f(gA.y), wA, a1);
            a2 = fmaf(b2f(gA.z), wA, a2); a3 = fmaf(b2f(gA.w), wA, a3);
            a0 = fmaf(b2f(gB.x), wB, a0); a1 = fmaf(b2f(gB.y), wB, a1);
            a2 = fmaf(b2f(gB.z), wB, a2); a3 = fmaf(b2f(gB.w), wB, a3);
        }
        for (; e0 < dcap; e0 += 4) {
            int e = e0 + esub;
            if (e < dcap) {
                int s = ssrc[e];
                float w = sw[e];
                ushort4 g = *(const ushort4*)(hrow + (size_t)s * 64);
                a0 = fmaf(b2f(g.x), w, a0); a1 = fmaf(b2f(g.y), w, a1);
                a2 = fmaf(b2f(g.z), w, a2); a3 = fmaf(b2f(g.w), w, a3);
            }
        }
        for (int j = MAXD + esub; j < deg; j += 4) {
            int s = srcs[beg + j];
            float v = as[s] + adv;
            v = v > 0.f ? v : 0.2f * v;
            float w = __expf(v - vmax) * rden;
            ushort4 g = *(const ushort4*)(hrow + (size_t)s * 64);
            a0 = fmaf(b2f(g.x), w, a0); a1 = fmaf(b2f(g.y), w, a1);
            a2 = fmaf(b2f(g.z), w, a2); a3 = fmaf(b2f(g.w), w, a3);
        }
        a0 += __shfl_xor(a0, 16, 64); a0 += __shfl_xor(a0, 32, 64);
        a1 += __shfl_xor(a1, 16, 64); a1 += __shfl_xor(a1, 32, 64);
        a2 += __shfl_xor(a2, 16, 64); a2 += __shfl_xor(a2, 32, 64);
        a3 += __shfl_xor(a3, 16, 64); a3 += __shfl_xor(a3, 32, 64);
        int g = batch[d];
        if (esub == 0) {
            float cntf = fmaxf((float)cnt_i[g], 1.f);
            float rc = 1.f / cntf;
            int cb = cg * 4;
            float4 o;
            o.x = (a0 + bias[cb + 0]) * rc;
            o.y = (a1 + bias[cb + 1]) * rc;
            o.z = (a2 + bias[cb + 2]) * rc;
            o.w = (a3 + bias[cb + 3]) * rc;
            *(float4*)&prow[wave][cb] = o;
        }
        if (lane == 0) gws[wave] = g;
    } else {
        if (lane == 0) gws[wave] = -1;
    }
    __syncthreads();
    if (threadIdx.x < 64) {
        int t = threadIdx.x;
        int g0 = gws[0];
        if (g0 >= 0 && gws[1] == g0 && gws[2] == g0 && gws[3] == g0) {
            atomicAdd(&outp[g0 * 64 + t],
                      prow[0][t] + prow[1][t] + prow[2][t] + prow[3][t]);
        } else {
            #pragma unroll
            for (int w2 = 0; w2 < 4; ++w2)
                if (gws[w2] >= 0) atomicAdd(&outp[gws[w2] * 64 + t], prow[w2][t]);
        }
    }
}

// ---------------- launch ----------------

extern "C" void kernel_launch(void* const* d_in, const int* in_sizes, int n_in,
                              void* d_out, int out_size, void* d_ws, size_t ws_size,
                              hipStream_t stream) {
    const float* x      = (const float*)d_in[0];
    const int*   ei     = (const int*)d_in[1];
    const int*   batch  = (const int*)d_in[2];
    const float* W1     = (const float*)d_in[3];
    const float* a_src1 = (const float*)d_in[4];
    const float* a_dst1 = (const float*)d_in[5];
    const float* b1     = (const float*)d_in[6];
    const float* W2     = (const float*)d_in[7];
    const float* a_src2 = (const float*)d_in[8];
    const float* a_dst2 = (const float*)d_in[9];
    const float* b2     = (const float*)d_in[10];
    float* out = (float*)d_out;

    const int N = in_sizes[0] / 128;    // 50000
    const int E = in_sizes[1] / 2;      // 800000
    const int F1 = 256;
    const int F2 = 64;
    const int T = E + N;
    const int NB = (N + 255) / 256;
    const int NCB = (T + 255) / 256;
    const int NG1 = (N + 63) / 64;

    // ---- workspace layout (float units) ----
    float* ws = (float*)d_ws;
    size_t o = 0;
    ushort_t* h1b   = (ushort_t*)(ws + o); o += (size_t)N * F1 / 2;
    ushort_t* out1b = (ushort_t*)(ws + o); o += (size_t)N * F1 / 2;
    ushort_t* h2b   = (ushort_t*)(ws + o); o += (size_t)N * F2 / 2;
    float* asrc1 = ws + o; o += (size_t)N * 4;
    float* adst1 = ws + o; o += (size_t)N * 4;
    float* asrc2 = ws + o; o += (size_t)N;
    float* adst2 = ws + o; o += (size_t)N;
    ushort_t* W1t = (ushort_t*)(ws + o); o += 256 * 128 / 2;
    ushort_t* W2t = (ushort_t*)(ws + o); o += 64 * 256 / 2;
    int* ib = (int*)(ws + o);
    size_t io = 0;
    int* deg      = ib + io; io += N;
    int* cursor   = ib + io; io += N;
    int* cnt_i    = ib + io; io += 32;
    int* rowstart = ib + io; io += N + 1;
    int* bsum     = ib + io; io += NB;
    int* srcs     = ib + io; io += T;
    (void)ws_size; (void)n_in; (void)out_size;

    // ---- zero counters; prep (transposes + hist + zero out + degree count) ----
    fill_i32<<<256, 256, 0, stream>>>(deg, 0, 2L * N + 32);
    prep_k<<<385 + NB + NCB, 256, 0, stream>>>(W1, W2, W1t, W2t, batch, cnt_i, out,
                                               ei, deg, N, E, NB);

    // ---- CSR scan ----
    scan1_k<<<NB, 256, 0, stream>>>(deg, bsum, N);
    scan3_k<<<NB, 256, 0, stream>>>(deg, bsum, rowstart, N, NB);

    // ---- gemm1 + scatter in one dispatch ----
    mega1_k<<<NG1 + NCB, 256, 0, stream>>>(x, W1t, h1b, a_src1, a_dst1,
                                           asrc1, adst1, N, NG1,
                                           ei, E, N, rowstart, cursor, srcs);

    // ---- layer 1 aggregation ----
    gat_agg4<<<(N + 3) / 4, 256, 0, stream>>>(h1b, rowstart, srcs, asrc1, adst1, b1, out1b, N);

    // ---- layer 2 (+ fused mean pool) ----
    gemm_mfma<2, 1, 256, true, 1><<<(N + 127) / 128, 128, 0, stream>>>(
        out1b, W2t, h2b, a_src2, a_dst2, asrc2, adst2, N);
    gat_agg1<<<(N + 3) / 4, 256, 0, stream>>>(h2b, rowstart, srcs, asrc2, adst2, b2,
                                              batch, cnt_i, out, N);
}